// Round 1
// baseline (1631.823 us; speedup 1.0000x reference)
//
#include <hip/hip_runtime.h>
#include <hip/hip_bf16.h>
#include <math.h>

#define T_TOK 8192      // b*l
#define L_SEQ 4096
#define DM    1024
#define DIN   2048
#define DSTATE 128
#define NH    32
#define HD    64
#define CH    64        // chunk length
#define NCH   64        // chunks per batch
#define NBC   128       // B * NCH
#define CONVD 2304
#define NPROJ 2336      // columns of in_proj we actually need (z gate unused)
#define PROJ_OFF 2048
#define DPROJ 4384

// ---------------- K1: in_proj GEMM (only cols 2048..4384) + softplus(dt) ----
__global__ __launch_bounds__(256) void k_inproj(const float* __restrict__ x,
    const float* __restrict__ w, const float* __restrict__ dt_bias,
    float* __restrict__ xbc, float* __restrict__ dtb) {
  __shared__ float As[16][65];   // As[k][m]
  __shared__ float Bs[16][64];   // Bs[k][n]
  int tid = threadIdx.x;
  int m0 = blockIdx.y * 64;
  int n0 = blockIdx.x * 64;
  int tx = tid & 15, ty = tid >> 4;
  float acc[4][4] = {};
  for (int k0 = 0; k0 < DM; k0 += 16) {
    {
      int c = tid & 15, r0 = tid >> 4;
      for (int i = 0; i < 4; i++) {
        int r = r0 + 16 * i;
        As[c][r] = x[(size_t)(m0 + r) * DM + k0 + c];
      }
    }
    {
      int nc = tid & 63, kr0 = tid >> 6;
      for (int i = 0; i < 4; i++) {
        int kr = kr0 + 4 * i;
        int ng = n0 + nc;
        float v = 0.f;
        if (ng < NPROJ) v = w[(size_t)(k0 + kr) * DPROJ + PROJ_OFF + ng];
        Bs[kr][nc] = v;
      }
    }
    __syncthreads();
    for (int k = 0; k < 16; k++) {
      float a[4], b[4];
      for (int i = 0; i < 4; i++) a[i] = As[k][ty * 4 + i];
      for (int j = 0; j < 4; j++) b[j] = Bs[k][tx * 4 + j];
      for (int i = 0; i < 4; i++)
        for (int j = 0; j < 4; j++) acc[i][j] += a[i] * b[j];
    }
    __syncthreads();
  }
  for (int i = 0; i < 4; i++) {
    int t = m0 + ty * 4 + i;
    for (int j = 0; j < 4; j++) {
      int ng = n0 + tx * 4 + j;
      float v = acc[i][j];
      if (ng < CONVD) {
        xbc[(size_t)t * CONVD + ng] = v;
      } else if (ng < NPROJ) {
        int h = ng - CONVD;
        float z = v + dt_bias[h];
        float sp = (z > 20.f) ? z : log1pf(__expf(z));
        dtb[t * NH + h] = sp;
      }
    }
  }
}

// ---------------- K2: depthwise causal conv(4) + bias + SiLU, split --------
__global__ __launch_bounds__(256) void k_conv(const float* __restrict__ xbc,
    const float* __restrict__ cw, const float* __restrict__ cb,
    float* __restrict__ xh, float* __restrict__ Bm, float* __restrict__ Cm) {
  int ch = blockIdx.x * 256 + threadIdx.x;
  if (ch >= CONVD) return;
  int t = blockIdx.y;
  int l = t & (L_SEQ - 1);
  float acc = cb[ch];
  for (int j = 0; j < 4; j++) {
    int ls = l - 3 + j;
    if (ls >= 0) acc += xbc[(size_t)(t - 3 + j) * CONVD + ch] * cw[j * CONVD + ch];
  }
  float sv = acc / (1.f + __expf(-acc));
  if (ch < DIN)             xh[(size_t)t * DIN + ch] = sv;
  else if (ch < DIN + DSTATE) Bm[t * DSTATE + ch - DIN] = sv;
  else                      Cm[t * DSTATE + ch - DIN - DSTATE] = sv;
}

// ---------------- K3: per-(b,c,h) inclusive cumsum of A*dt + chunk decay ----
__global__ void k_acum(const float* __restrict__ dtb, const float* __restrict__ A_log,
                       float* __restrict__ acum, float* __restrict__ echunk) {
  int h = threadIdx.x;     // 32
  int bc = blockIdx.x;     // 0..127
  int base = bc * CH;
  float a = -__expf(A_log[h]);
  float s = 0.f;
  for (int l = 0; l < CH; l++) {
    s += a * dtb[(base + l) * NH + h];
    acum[(base + l) * NH + h] = s;
  }
  echunk[bc * NH + h] = __expf(s);
}

// ---------------- K4: Gram matrix G[l,s] = C[l].B[s] per chunk -------------
__global__ __launch_bounds__(256) void k_gmat(const float* __restrict__ Bm,
    const float* __restrict__ Cm, float* __restrict__ G) {
  __shared__ float Cst[DSTATE][64];   // transposed C, swizzled cols
  __shared__ float Bs[32][DSTATE];
  int bc = blockIdx.x;
  int sb = blockIdx.y * 32;
  int base = bc * CH;
  int tid = threadIdx.x;
  for (int i = 0; i < 32; i++) {
    int e = tid + 256 * i;
    int r = e >> 7, cc = e & 127;      // r = l, cc = n
    Cst[cc][(r + cc) & 63] = Cm[(size_t)(base + r) * DSTATE + cc];
  }
  for (int i = 0; i < 16; i++) {
    int e = tid + 256 * i;
    int r = e >> 7, cc = e & 127;
    Bs[r][cc] = Bm[(size_t)(base + sb + r) * DSTATE + cc];
  }
  __syncthreads();
  int l = tid & 63;
  int sg = tid >> 6;
  int s0 = sg * 8;
  float acc[8] = {};
  for (int n = 0; n < DSTATE; n++) {
    float cv = Cst[n][(l + n) & 63];
    for (int j = 0; j < 8; j++) acc[j] += cv * Bs[s0 + j][n];
  }
  for (int j = 0; j < 8; j++)
    G[(size_t)bc * 4096 + l * 64 + sb + s0 + j] = acc[j];
}

// ---------------- K5: Y_diag + xh*D ----------------------------------------
__global__ __launch_bounds__(256) void k_ydiag(const float* __restrict__ xh,
    const float* __restrict__ dtb, const float* __restrict__ acum,
    const float* __restrict__ G, const float* __restrict__ Dp,
    float* __restrict__ y) {
  __shared__ float xd[CH][65];
  __shared__ float Gs[CH][65];
  __shared__ float acv[CH];
  __shared__ float dts[CH];
  int bc = blockIdx.x, h = blockIdx.y;
  int base = bc * CH;
  int tid = threadIdx.x;
  if (tid < CH) {
    dts[tid] = dtb[(base + tid) * NH + h];
    acv[tid] = acum[(base + tid) * NH + h];
  }
  for (int i = 0; i < 16; i++) {
    int e = tid + 256 * i, r = e >> 6, cc = e & 63;
    Gs[r][cc] = G[(size_t)bc * 4096 + e];
  }
  __syncthreads();
  for (int i = 0; i < 16; i++) {
    int e = tid + 256 * i, s = e >> 6, p = e & 63;
    xd[s][p] = xh[(size_t)(base + s) * DIN + h * HD + p] * dts[s];
  }
  __syncthreads();
  int l = tid & 63, pg = tid >> 6, p0 = pg * 16;
  float acc[16] = {};
  float al = acv[l];
  for (int s = 0; s <= l; s++) {
    float wv = Gs[l][s] * __expf(al - acv[s]);
    for (int j = 0; j < 16; j++) acc[j] += wv * xd[s][p0 + j];
  }
  float Dh = Dp[h];
  for (int j = 0; j < 16; j++) {
    size_t off = (size_t)(base + l) * DIN + h * HD + p0 + j;
    y[off] = acc[j] + xh[off] * Dh;
  }
}

// ---------------- K6a: per-chunk states (bf16) ------------------------------
__global__ __launch_bounds__(256) void k_states(const float* __restrict__ xh,
    const float* __restrict__ dtb, const float* __restrict__ acum,
    const float* __restrict__ Bm, __hip_bfloat16* __restrict__ states) {
  __shared__ float Bs[CH][DSTATE];
  __shared__ float xd[CH][65];
  __shared__ float dec[CH];
  __shared__ float dts[CH];
  int bc = blockIdx.x, h = blockIdx.y;
  int base = bc * CH;
  int tid = threadIdx.x;
  if (tid < CH) dts[tid] = dtb[(base + tid) * NH + h];
  __syncthreads();
  if (tid < CH) {
    float al = acum[(base + tid) * NH + h];
    float alast = acum[(base + CH - 1) * NH + h];
    dec[tid] = __expf(alast - al);
  }
  for (int i = 0; i < 32; i++) {
    int e = tid + 256 * i; int r = e >> 7, cc = e & 127;
    Bs[r][cc] = Bm[(size_t)(base + r) * DSTATE + cc];
  }
  for (int i = 0; i < 16; i++) {
    int e = tid + 256 * i; int s = e >> 6, p = e & 63;
    xd[s][p] = xh[(size_t)(base + s) * DIN + h * HD + p] * dts[s];
  }
  __syncthreads();
  int n = tid & 127;
  int pg = tid >> 7;     // 0..1
  int p0 = pg * 32;
  float acc[32] = {};
  for (int l = 0; l < CH; l++) {
    float bv = Bs[l][n] * dec[l];
    for (int j = 0; j < 32; j++) acc[j] += bv * xd[l][p0 + j];
  }
  size_t sbase = ((size_t)bc * NH + h) * (HD * DSTATE);
  for (int j = 0; j < 32; j++)
    states[sbase + (size_t)(p0 + j) * DSTATE + n] = __float2bfloat16(acc[j]);
}

// ---------------- K6b: inter-chunk scan (in-place: states -> incoming) -----
__global__ __launch_bounds__(256) void k_scan(__hip_bfloat16* __restrict__ states,
    const float* __restrict__ echunk) {
  int idx = blockIdx.x * 256 + threadIdx.x;   // 524288
  int n = idx & 127;
  int p = (idx >> 7) & 63;
  int h = (idx >> 13) & 31;
  int b = idx >> 18;
  float run = 0.f;
  for (int c = 0; c < NCH; c++) {
    int bc = b * NCH + c;
    size_t off = (((size_t)bc * NH + h) * HD + p) * DSTATE + n;
    float tmp = __bfloat162float(states[off]);
    states[off] = __float2bfloat16(run);
    run = run * echunk[bc * NH + h] + tmp;
  }
}

// ---------------- K6c: Y_off += C . state_in * exp(acum) -------------------
__global__ __launch_bounds__(256) void k_yoff(const __hip_bfloat16* __restrict__ states,
    const float* __restrict__ Cm, const float* __restrict__ acum,
    float* __restrict__ y) {
  __shared__ float Cs[CH][DSTATE];            // swizzled cols
  __shared__ __hip_bfloat16 Ssb[HD][DSTATE];
  __shared__ float aout[CH];
  int bc = blockIdx.x, h = blockIdx.y;
  int base = bc * CH;
  int tid = threadIdx.x;
  if (tid < CH) aout[tid] = __expf(acum[(base + tid) * NH + h]);
  size_t sbase = ((size_t)bc * NH + h) * (HD * DSTATE);
  for (int i = 0; i < 32; i++) {
    int e = tid + 256 * i;
    int r = e >> 7, cc = e & 127;
    Cs[r][(cc + r) & 127] = Cm[(size_t)(base + r) * DSTATE + cc];
    Ssb[r][cc] = states[sbase + e];
  }
  __syncthreads();
  int l = tid & 63, pg = tid >> 6, p0 = pg * 16;
  float acc[16] = {};
  for (int n = 0; n < DSTATE; n++) {
    float cv = Cs[l][(n + l) & 127];
    for (int j = 0; j < 16; j++)
      acc[j] += cv * __bfloat162float(Ssb[p0 + j][n]);
  }
  float ao = aout[l];
  for (int j = 0; j < 16; j++) {
    size_t off = (size_t)(base + l) * DIN + h * HD + p0 + j;
    y[off] += ao * acc[j];
  }
}

// ---------------- K7: out_proj GEMM ----------------------------------------
__global__ __launch_bounds__(256) void k_outproj(const float* __restrict__ y,
    const float* __restrict__ w, float* __restrict__ out) {
  __shared__ float As[16][65];
  __shared__ float Bs[16][64];
  int tid = threadIdx.x;
  int m0 = blockIdx.y * 64;
  int n0 = blockIdx.x * 64;
  int tx = tid & 15, ty = tid >> 4;
  float acc[4][4] = {};
  for (int k0 = 0; k0 < DIN; k0 += 16) {
    {
      int c = tid & 15, r0 = tid >> 4;
      for (int i = 0; i < 4; i++) {
        int r = r0 + 16 * i;
        As[c][r] = y[(size_t)(m0 + r) * DIN + k0 + c];
      }
    }
    {
      int nc = tid & 63, kr0 = tid >> 6;
      for (int i = 0; i < 4; i++) {
        int kr = kr0 + 4 * i;
        Bs[kr][nc] = w[(size_t)(k0 + kr) * DM + n0 + nc];
      }
    }
    __syncthreads();
    for (int k = 0; k < 16; k++) {
      float a[4], b[4];
      for (int i = 0; i < 4; i++) a[i] = As[k][ty * 4 + i];
      for (int j = 0; j < 4; j++) b[j] = Bs[k][tx * 4 + j];
      for (int i = 0; i < 4; i++)
        for (int j = 0; j < 4; j++) acc[i][j] += a[i] * b[j];
    }
    __syncthreads();
  }
  for (int i = 0; i < 4; i++)
    for (int j = 0; j < 4; j++)
      out[(size_t)(m0 + ty * 4 + i) * DM + n0 + tx * 4 + j] = acc[i][j];
}

extern "C" void kernel_launch(void* const* d_in, const int* in_sizes, int n_in,
                              void* d_out, int out_size, void* d_ws, size_t ws_size,
                              hipStream_t stream) {
  const float* x       = (const float*)d_in[0];
  const float* in_w    = (const float*)d_in[1];
  const float* conv_w  = (const float*)d_in[2];
  const float* conv_b  = (const float*)d_in[3];
  const float* dt_bias = (const float*)d_in[4];
  const float* A_log   = (const float*)d_in[5];
  const float* Dp      = (const float*)d_in[6];
  const float* out_w   = (const float*)d_in[7];
  float* out = (float*)d_out;

  float* xbc    = (float*)d_ws;                        // T*2304 (later reused as y)
  float* dtb    = xbc + (size_t)T_TOK * CONVD;         // T*32
  float* acum   = dtb + (size_t)T_TOK * NH;            // T*32
  float* echunk = acum + (size_t)T_TOK * NH;           // NBC*32
  float* xh     = echunk + (size_t)NBC * NH;           // T*2048
  float* Bm     = xh + (size_t)T_TOK * DIN;            // T*128
  float* Cm     = Bm + (size_t)T_TOK * DSTATE;         // T*128
  float* G      = Cm + (size_t)T_TOK * DSTATE;         // NBC*4096
  __hip_bfloat16* states = (__hip_bfloat16*)(G + (size_t)NBC * CH * CH); // NBC*NH*64*128
  float* y = xbc;  // alias: xbc dead after k_conv

  k_inproj <<<dim3(37, 128),  256, 0, stream>>>(x, in_w, dt_bias, xbc, dtb);
  k_conv   <<<dim3(9, T_TOK), 256, 0, stream>>>(xbc, conv_w, conv_b, xh, Bm, Cm);
  k_acum   <<<dim3(NBC),       32, 0, stream>>>(dtb, A_log, acum, echunk);
  k_gmat   <<<dim3(NBC, 2),   256, 0, stream>>>(Bm, Cm, G);
  k_ydiag  <<<dim3(NBC, NH),  256, 0, stream>>>(xh, dtb, acum, G, Dp, y);
  k_states <<<dim3(NBC, NH),  256, 0, stream>>>(xh, dtb, acum, Bm, states);
  k_scan   <<<dim3(2048),     256, 0, stream>>>(states, echunk);
  k_yoff   <<<dim3(NBC, NH),  256, 0, stream>>>(states, Cm, acum, y);
  k_outproj<<<dim3(16, 128),  256, 0, stream>>>(y, out_w, out);
}

// Round 2
// 721.553 us; speedup vs baseline: 2.2615x; 2.2615x over previous
//
#include <hip/hip_runtime.h>
#include <hip/hip_bf16.h>
#include <math.h>
#include <stdint.h>

#define T_TOK 8192      // b*l
#define L_SEQ 4096
#define DM    1024
#define DIN   2048
#define DSTATE 128
#define NH    32
#define HD    64
#define CH    64        // chunk length
#define NCH   64        // chunks per batch
#define NBC   128       // B * NCH
#define CONVD 2304
#define NPROJ 2336      // columns of in_proj we actually need (z gate unused)
#define NPAD  2432      // NPROJ padded to multiple of 128
#define PROJ_OFF 2048
#define DPROJ 4384

typedef __bf16 bf16x8 __attribute__((ext_vector_type(8)));
typedef float f32x4 __attribute__((ext_vector_type(4)));

__device__ __forceinline__ void gload_lds16(const void* g, void* l) {
  __builtin_amdgcn_global_load_lds(
      (const __attribute__((address_space(1))) void*)(uintptr_t)g,
      (__attribute__((address_space(3))) void*)(uintptr_t)l, 16, 0, 0);
}

// ---------------- cast fp32 -> bf16 (elementwise) ---------------------------
__global__ __launch_bounds__(256) void k_cast(const float* __restrict__ src,
    __hip_bfloat16* __restrict__ dst, int n4) {
  int i = (blockIdx.x * 256 + threadIdx.x) * 4;
  if (i < n4 * 4) {
    float4 v = *(const float4*)(src + i);
    dst[i + 0] = __float2bfloat16(v.x);
    dst[i + 1] = __float2bfloat16(v.y);
    dst[i + 2] = __float2bfloat16(v.z);
    dst[i + 3] = __float2bfloat16(v.w);
  }
}

// ---------------- transpose + cast: wt[n][k] = w[k][colOff+n] ---------------
__global__ __launch_bounds__(256) void k_wtrans(const float* __restrict__ w,
    __hip_bfloat16* __restrict__ wt, int K, int ldsrc, int colOff, int ncols) {
  __shared__ float s[64][65];
  int k0 = blockIdx.x * 64, n0 = blockIdx.y * 64;
  int c = threadIdx.x & 63, r0 = threadIdx.x >> 6;
  for (int i = 0; i < 16; i++) {
    int r = r0 + 4 * i;
    int ng = n0 + c;
    s[r][c] = (ng < ncols) ? w[(size_t)(k0 + r) * ldsrc + colOff + ng] : 0.f;
  }
  __syncthreads();
  for (int i = 0; i < 16; i++) {
    int a = r0 + 4 * i;            // n within tile
    wt[(size_t)(n0 + a) * K + k0 + c] = __float2bfloat16(s[c][a]);
  }
}

// ---------------- MFMA GEMM: C[M][N] = A[M][K] * Bt[N][K]^T -----------------
// 128x128 tile, BK=64, 256 threads (4 waves, each 64x64 via 4x4 mfma 16x16x32)
template <int KDIM, bool SPLIT>
__global__ __launch_bounds__(256) void k_gemm_bt(
    const __hip_bfloat16* __restrict__ A, const __hip_bfloat16* __restrict__ Bt,
    float* __restrict__ C, float* __restrict__ dtb, const float* __restrict__ dt_bias,
    int NLD) {
  __shared__ __attribute__((aligned(16))) __hip_bfloat16 sA[128 * 64];
  __shared__ __attribute__((aligned(16))) __hip_bfloat16 sB[128 * 64];
  int tid = threadIdx.x;
  int wid = tid >> 6, lane = tid & 63;
  int m0 = blockIdx.y * 128, n0 = blockIdx.x * 128;
  int wm = (wid >> 1) * 64, wn = (wid & 1) * 64;
  int r15 = lane & 15, quad = lane >> 4;

  // staging lane geometry (wave-uniform LDS base + lane*16)
  int srow = lane >> 3;             // 0..7 within 8-row chunk
  int kcs = lane & 7;               // stored chunk

  f32x4 acc[4][4];
  f32x4 zz = {0.f, 0.f, 0.f, 0.f};
  for (int mi = 0; mi < 4; mi++)
    for (int ni = 0; ni < 4; ni++) acc[mi][ni] = zz;

  const __hip_bfloat16* Abase = A + (size_t)m0 * KDIM;
  const __hip_bfloat16* Bbase = Bt + (size_t)n0 * KDIM;

  for (int k0 = 0; k0 < KDIM; k0 += 64) {
    // stage A and Bt tiles (128 rows x 64 k each), XOR-swizzled granules
    for (int c = 0; c < 4; c++) {
      int R0 = (wid * 4 + c) * 8;
      int row = R0 + srow;
      int kcg = kcs ^ (row & 7);
      gload_lds16(Abase + (size_t)row * KDIM + k0 + kcg * 8, &sA[R0 * 64]);
      gload_lds16(Bbase + (size_t)row * KDIM + k0 + kcg * 8, &sB[R0 * 64]);
    }
    __syncthreads();
#pragma unroll
    for (int s = 0; s < 2; s++) {
      int sw = ((s << 2) | quad) ^ (r15 & 7);
      bf16x8 af[4], bfr[4];
#pragma unroll
      for (int mi = 0; mi < 4; mi++)
        af[mi] = *reinterpret_cast<const bf16x8*>(&sA[(wm + mi * 16 + r15) * 64 + sw * 8]);
#pragma unroll
      for (int ni = 0; ni < 4; ni++)
        bfr[ni] = *reinterpret_cast<const bf16x8*>(&sB[(wn + ni * 16 + r15) * 64 + sw * 8]);
#pragma unroll
      for (int mi = 0; mi < 4; mi++)
#pragma unroll
        for (int ni = 0; ni < 4; ni++)
          acc[mi][ni] = __builtin_amdgcn_mfma_f32_16x16x32_bf16(af[mi], bfr[ni], acc[mi][ni], 0, 0, 0);
    }
    __syncthreads();
  }

  // epilogue: D[row=quad*4+i][col=r15] per 16x16 tile
#pragma unroll
  for (int mi = 0; mi < 4; mi++) {
#pragma unroll
    for (int i = 0; i < 4; i++) {
      int t = m0 + wm + mi * 16 + quad * 4 + i;
#pragma unroll
      for (int ni = 0; ni < 4; ni++) {
        int n = n0 + wn + ni * 16 + r15;
        float v = acc[mi][ni][i];
        if (SPLIT) {
          if (n < CONVD) {
            C[(size_t)t * CONVD + n] = v;
          } else if (n < NPROJ) {
            int h = n - CONVD;
            float z = v + dt_bias[h];
            float sp = (z > 20.f) ? z : log1pf(__expf(z));
            dtb[t * NH + h] = sp;
          }
        } else {
          C[(size_t)t * NLD + n] = v;
        }
      }
    }
  }
}

// ---------------- K2: depthwise causal conv(4) + bias + SiLU, split --------
__global__ __launch_bounds__(256) void k_conv(const float* __restrict__ xbc,
    const float* __restrict__ cw, const float* __restrict__ cb,
    float* __restrict__ xh, float* __restrict__ Bm, float* __restrict__ Cm) {
  int ch = blockIdx.x * 256 + threadIdx.x;
  if (ch >= CONVD) return;
  int t = blockIdx.y;
  int l = t & (L_SEQ - 1);
  float acc = cb[ch];
  for (int j = 0; j < 4; j++) {
    int ls = l - 3 + j;
    if (ls >= 0) acc += xbc[(size_t)(t - 3 + j) * CONVD + ch] * cw[j * CONVD + ch];
  }
  float sv = acc / (1.f + __expf(-acc));
  if (ch < DIN)             xh[(size_t)t * DIN + ch] = sv;
  else if (ch < DIN + DSTATE) Bm[t * DSTATE + ch - DIN] = sv;
  else                      Cm[t * DSTATE + ch - DIN - DSTATE] = sv;
}

// ---------------- K3: per-(b,c,h) inclusive cumsum of A*dt + chunk decay ----
__global__ void k_acum(const float* __restrict__ dtb, const float* __restrict__ A_log,
                       float* __restrict__ acum, float* __restrict__ echunk) {
  int h = threadIdx.x;     // 32
  int bc = blockIdx.x;     // 0..127
  int base = bc * CH;
  float a = -__expf(A_log[h]);
  float s = 0.f;
  for (int l = 0; l < CH; l++) {
    s += a * dtb[(base + l) * NH + h];
    acum[(base + l) * NH + h] = s;
  }
  echunk[bc * NH + h] = __expf(s);
}

// ---------------- K4: Gram matrix G[l,s] = C[l].B[s] per chunk -------------
__global__ __launch_bounds__(256) void k_gmat(const float* __restrict__ Bm,
    const float* __restrict__ Cm, float* __restrict__ G) {
  __shared__ float Cst[DSTATE][64];   // transposed C, swizzled cols
  __shared__ float Bs[32][DSTATE];
  int bc = blockIdx.x;
  int sb = blockIdx.y * 32;
  int base = bc * CH;
  int tid = threadIdx.x;
  for (int i = 0; i < 32; i++) {
    int e = tid + 256 * i;
    int r = e >> 7, cc = e & 127;      // r = l, cc = n
    Cst[cc][(r + cc) & 63] = Cm[(size_t)(base + r) * DSTATE + cc];
  }
  for (int i = 0; i < 16; i++) {
    int e = tid + 256 * i;
    int r = e >> 7, cc = e & 127;
    Bs[r][cc] = Bm[(size_t)(base + sb + r) * DSTATE + cc];
  }
  __syncthreads();
  int l = tid & 63;
  int sg = tid >> 6;
  int s0 = sg * 8;
  float acc[8] = {};
  for (int n = 0; n < DSTATE; n++) {
    float cv = Cst[n][(l + n) & 63];
    for (int j = 0; j < 8; j++) acc[j] += cv * Bs[s0 + j][n];
  }
  for (int j = 0; j < 8; j++)
    G[(size_t)bc * 4096 + l * 64 + sb + s0 + j] = acc[j];
}

// ---------------- K5: Y_diag + xh*D ----------------------------------------
__global__ __launch_bounds__(256) void k_ydiag(const float* __restrict__ xh,
    const float* __restrict__ dtb, const float* __restrict__ acum,
    const float* __restrict__ G, const float* __restrict__ Dp,
    float* __restrict__ y) {
  __shared__ float xd[CH][65];
  __shared__ float Gs[CH][65];
  __shared__ float acv[CH];
  __shared__ float dts[CH];
  int bc = blockIdx.x, h = blockIdx.y;
  int base = bc * CH;
  int tid = threadIdx.x;
  if (tid < CH) {
    dts[tid] = dtb[(base + tid) * NH + h];
    acv[tid] = acum[(base + tid) * NH + h];
  }
  for (int i = 0; i < 16; i++) {
    int e = tid + 256 * i, r = e >> 6, cc = e & 63;
    Gs[r][cc] = G[(size_t)bc * 4096 + e];
  }
  __syncthreads();
  for (int i = 0; i < 16; i++) {
    int e = tid + 256 * i, s = e >> 6, p = e & 63;
    xd[s][p] = xh[(size_t)(base + s) * DIN + h * HD + p] * dts[s];
  }
  __syncthreads();
  int l = tid & 63, pg = tid >> 6, p0 = pg * 16;
  float acc[16] = {};
  float al = acv[l];
  for (int s = 0; s <= l; s++) {
    float wv = Gs[l][s] * __expf(al - acv[s]);
    for (int j = 0; j < 16; j++) acc[j] += wv * xd[s][p0 + j];
  }
  float Dh = Dp[h];
  for (int j = 0; j < 16; j++) {
    size_t off = (size_t)(base + l) * DIN + h * HD + p0 + j;
    y[off] = acc[j] + xh[off] * Dh;
  }
}

// ---------------- K6a: per-chunk states (bf16) ------------------------------
__global__ __launch_bounds__(256) void k_states(const float* __restrict__ xh,
    const float* __restrict__ dtb, const float* __restrict__ acum,
    const float* __restrict__ Bm, __hip_bfloat16* __restrict__ states) {
  __shared__ float Bs[CH][DSTATE];
  __shared__ float xd[CH][65];
  __shared__ float dec[CH];
  __shared__ float dts[CH];
  int bc = blockIdx.x, h = blockIdx.y;
  int base = bc * CH;
  int tid = threadIdx.x;
  if (tid < CH) dts[tid] = dtb[(base + tid) * NH + h];
  __syncthreads();
  if (tid < CH) {
    float al = acum[(base + tid) * NH + h];
    float alast = acum[(base + CH - 1) * NH + h];
    dec[tid] = __expf(alast - al);
  }
  for (int i = 0; i < 32; i++) {
    int e = tid + 256 * i; int r = e >> 7, cc = e & 127;
    Bs[r][cc] = Bm[(size_t)(base + r) * DSTATE + cc];
  }
  for (int i = 0; i < 16; i++) {
    int e = tid + 256 * i; int s = e >> 6, p = e & 63;
    xd[s][p] = xh[(size_t)(base + s) * DIN + h * HD + p] * dts[s];
  }
  __syncthreads();
  int n = tid & 127;
  int pg = tid >> 7;     // 0..1
  int p0 = pg * 32;
  float acc[32] = {};
  for (int l = 0; l < CH; l++) {
    float bv = Bs[l][n] * dec[l];
    for (int j = 0; j < 32; j++) acc[j] += bv * xd[l][p0 + j];
  }
  size_t sbase = ((size_t)bc * NH + h) * (HD * DSTATE);
  for (int j = 0; j < 32; j++)
    states[sbase + (size_t)(p0 + j) * DSTATE + n] = __float2bfloat16(acc[j]);
}

// ---------------- K6b: inter-chunk scan (in-place: states -> incoming) -----
__global__ __launch_bounds__(256) void k_scan(__hip_bfloat16* __restrict__ states,
    const float* __restrict__ echunk) {
  int idx = blockIdx.x * 256 + threadIdx.x;   // 524288
  int n = idx & 127;
  int p = (idx >> 7) & 63;
  int h = (idx >> 13) & 31;
  int b = idx >> 18;
  float run = 0.f;
  for (int c = 0; c < NCH; c++) {
    int bc = b * NCH + c;
    size_t off = (((size_t)bc * NH + h) * HD + p) * DSTATE + n;
    float tmp = __bfloat162float(states[off]);
    states[off] = __float2bfloat16(run);
    run = run * echunk[bc * NH + h] + tmp;
  }
}

// ---------------- K6c: y_final = (y_diag + C.state_in*exp(acum)) -> bf16 ---
__global__ __launch_bounds__(256) void k_yoff(const __hip_bfloat16* __restrict__ states,
    const float* __restrict__ Cm, const float* __restrict__ acum,
    const float* __restrict__ y, __hip_bfloat16* __restrict__ yb) {
  __shared__ float Cs[CH][DSTATE];            // swizzled cols
  __shared__ __hip_bfloat16 Ssb[HD][DSTATE];
  __shared__ float aout[CH];
  int bc = blockIdx.x, h = blockIdx.y;
  int base = bc * CH;
  int tid = threadIdx.x;
  if (tid < CH) aout[tid] = __expf(acum[(base + tid) * NH + h]);
  size_t sbase = ((size_t)bc * NH + h) * (HD * DSTATE);
  for (int i = 0; i < 32; i++) {
    int e = tid + 256 * i;
    int r = e >> 7, cc = e & 127;
    Cs[r][(cc + r) & 127] = Cm[(size_t)(base + r) * DSTATE + cc];
    Ssb[r][cc] = states[sbase + e];
  }
  __syncthreads();
  int l = tid & 63, pg = tid >> 6, p0 = pg * 16;
  float acc[16] = {};
  for (int n = 0; n < DSTATE; n++) {
    float cv = Cs[l][(n + l) & 127];
    for (int j = 0; j < 16; j++)
      acc[j] += cv * __bfloat162float(Ssb[p0 + j][n]);
  }
  float ao = aout[l];
  for (int j = 0; j < 16; j++) {
    size_t off = (size_t)(base + l) * DIN + h * HD + p0 + j;
    yb[off] = __float2bfloat16(y[off] + ao * acc[j]);
  }
}

extern "C" void kernel_launch(void* const* d_in, const int* in_sizes, int n_in,
                              void* d_out, int out_size, void* d_ws, size_t ws_size,
                              hipStream_t stream) {
  const float* x       = (const float*)d_in[0];
  const float* in_w    = (const float*)d_in[1];
  const float* conv_w  = (const float*)d_in[2];
  const float* conv_b  = (const float*)d_in[3];
  const float* dt_bias = (const float*)d_in[4];
  const float* A_log   = (const float*)d_in[5];
  const float* Dp      = (const float*)d_in[6];
  const float* out_w   = (const float*)d_in[7];
  float* out = (float*)d_out;

  float* xbc    = (float*)d_ws;                        // T*2304 (later reused as y)
  float* dtb    = xbc + (size_t)T_TOK * CONVD;         // T*32
  float* acum   = dtb + (size_t)T_TOK * NH;            // T*32
  float* echunk = acum + (size_t)T_TOK * NH;           // NBC*32
  float* xh     = echunk + (size_t)NBC * NH;           // T*2048
  float* Bm     = xh + (size_t)T_TOK * DIN;            // T*128
  float* Cm     = Bm + (size_t)T_TOK * DSTATE;         // T*128
  float* G      = Cm + (size_t)T_TOK * DSTATE;         // NBC*4096
  __hip_bfloat16* states = (__hip_bfloat16*)(G + (size_t)NBC * CH * CH); // NBC*NH*64*128 bf16
  float* wend   = (float*)(states + (size_t)NBC * NH * HD * DSTATE);
  __hip_bfloat16* wib = (__hip_bfloat16*)wend;               // NPAD*1024 bf16
  __hip_bfloat16* wob = (__hip_bfloat16*)(wend + (size_t)NPAD * DM / 2); // 1024*2048 bf16
  float* y = xbc;                                   // alias: xbc dead after k_conv
  __hip_bfloat16* xb = (__hip_bfloat16*)states;     // alias: xb dead before k_states
  __hip_bfloat16* yb = (__hip_bfloat16*)xh;         // alias: xh dead after k_states

  k_cast   <<<dim3(T_TOK * DM / 1024), 256, 0, stream>>>(x, xb, T_TOK * DM / 4);
  k_wtrans <<<dim3(16, 38), 256, 0, stream>>>(in_w, wib, DM, DPROJ, PROJ_OFF, NPROJ);
  k_wtrans <<<dim3(32, 16), 256, 0, stream>>>(out_w, wob, DIN, DM, 0, DM);
  k_gemm_bt<DM, true><<<dim3(NPAD / 128, T_TOK / 128), 256, 0, stream>>>(
      xb, wib, xbc, dtb, dt_bias, 0);
  k_conv   <<<dim3(9, T_TOK), 256, 0, stream>>>(xbc, conv_w, conv_b, xh, Bm, Cm);
  k_acum   <<<dim3(NBC),       32, 0, stream>>>(dtb, A_log, acum, echunk);
  k_gmat   <<<dim3(NBC, 2),   256, 0, stream>>>(Bm, Cm, G);
  k_ydiag  <<<dim3(NBC, NH),  256, 0, stream>>>(xh, dtb, acum, G, Dp, y);
  k_states <<<dim3(NBC, NH),  256, 0, stream>>>(xh, dtb, acum, Bm, states);
  k_scan   <<<dim3(2048),     256, 0, stream>>>(states, echunk);
  k_yoff   <<<dim3(NBC, NH),  256, 0, stream>>>(states, Cm, acum, y, yb);
  k_gemm_bt<DIN, false><<<dim3(DM / 128, T_TOK / 128), 256, 0, stream>>>(
      yb, wob, out, 0, 0, DM);
}

// Round 3
// 407.001 us; speedup vs baseline: 4.0094x; 1.7729x over previous
//
#include <hip/hip_runtime.h>
#include <hip/hip_bf16.h>
#include <math.h>
#include <stdint.h>

#define T_TOK 8192      // b*l
#define L_SEQ 4096
#define DM    1024
#define DIN   2048
#define DSTATE 128
#define NH    32
#define HD    64
#define CH    64        // chunk length
#define NCH   64        // chunks per batch
#define NBC   128       // B * NCH
#define CONVD 2304
#define NPROJ 2336      // columns of in_proj we actually need (z gate unused)
#define NPAD  2432      // NPROJ padded to multiple of 128
#define PROJ_OFF 2048
#define DPROJ 4384

typedef __bf16 bf16x8 __attribute__((ext_vector_type(8)));
typedef float f32x4 __attribute__((ext_vector_type(4)));

__device__ __forceinline__ void gload_lds16(const void* g, void* l) {
  __builtin_amdgcn_global_load_lds(
      (const __attribute__((address_space(1))) void*)(uintptr_t)g,
      (__attribute__((address_space(3))) void*)(uintptr_t)l, 16, 0, 0);
}

// ---------------- cast fp32 -> bf16 (elementwise) ---------------------------
__global__ __launch_bounds__(256) void k_cast(const float* __restrict__ src,
    __hip_bfloat16* __restrict__ dst, int n4) {
  int i = (blockIdx.x * 256 + threadIdx.x) * 4;
  if (i < n4 * 4) {
    float4 v = *(const float4*)(src + i);
    dst[i + 0] = __float2bfloat16(v.x);
    dst[i + 1] = __float2bfloat16(v.y);
    dst[i + 2] = __float2bfloat16(v.z);
    dst[i + 3] = __float2bfloat16(v.w);
  }
}

// ---------------- transpose + cast: wt[n][k] = w[k][colOff+n] ---------------
__global__ __launch_bounds__(256) void k_wtrans(const float* __restrict__ w,
    __hip_bfloat16* __restrict__ wt, int K, int ldsrc, int colOff, int ncols) {
  __shared__ float s[64][65];
  int k0 = blockIdx.x * 64, n0 = blockIdx.y * 64;
  int c = threadIdx.x & 63, r0 = threadIdx.x >> 6;
  for (int i = 0; i < 16; i++) {
    int r = r0 + 4 * i;
    int ng = n0 + c;
    s[r][c] = (ng < ncols) ? w[(size_t)(k0 + r) * ldsrc + colOff + ng] : 0.f;
  }
  __syncthreads();
  for (int i = 0; i < 16; i++) {
    int a = r0 + 4 * i;            // n within tile
    wt[(size_t)(n0 + a) * K + k0 + c] = __float2bfloat16(s[c][a]);
  }
}

// ---------------- MFMA GEMM: C[M][N] = A[M][K] * Bt[N][K]^T -----------------
// 128x128 tile, BK=64, 256 threads (4 waves, each 64x64 via 4x4 mfma 16x16x32)
template <int KDIM, bool SPLIT>
__global__ __launch_bounds__(256) void k_gemm_bt(
    const __hip_bfloat16* __restrict__ A, const __hip_bfloat16* __restrict__ Bt,
    float* __restrict__ C, __hip_bfloat16* __restrict__ Cb16,
    float* __restrict__ dtb, const float* __restrict__ dt_bias, int NLD) {
  __shared__ __attribute__((aligned(16))) __hip_bfloat16 sA[128 * 64];
  __shared__ __attribute__((aligned(16))) __hip_bfloat16 sB[128 * 64];
  int tid = threadIdx.x;
  int wid = tid >> 6, lane = tid & 63;
  int m0 = blockIdx.y * 128, n0 = blockIdx.x * 128;
  int wm = (wid >> 1) * 64, wn = (wid & 1) * 64;
  int r15 = lane & 15, quad = lane >> 4;

  int srow = lane >> 3;             // 0..7 within 8-row chunk
  int kcs = lane & 7;               // stored chunk

  f32x4 acc[4][4];
  f32x4 zz = {0.f, 0.f, 0.f, 0.f};
  for (int mi = 0; mi < 4; mi++)
    for (int ni = 0; ni < 4; ni++) acc[mi][ni] = zz;

  const __hip_bfloat16* Abase = A + (size_t)m0 * KDIM;
  const __hip_bfloat16* Bbase = Bt + (size_t)n0 * KDIM;

  for (int k0 = 0; k0 < KDIM; k0 += 64) {
    for (int c = 0; c < 4; c++) {
      int R0 = (wid * 4 + c) * 8;
      int row = R0 + srow;
      int kcg = kcs ^ (row & 7);
      gload_lds16(Abase + (size_t)row * KDIM + k0 + kcg * 8, &sA[R0 * 64]);
      gload_lds16(Bbase + (size_t)row * KDIM + k0 + kcg * 8, &sB[R0 * 64]);
    }
    __syncthreads();
#pragma unroll
    for (int s = 0; s < 2; s++) {
      int sw = ((s << 2) | quad) ^ (r15 & 7);
      bf16x8 af[4], bfr[4];
#pragma unroll
      for (int mi = 0; mi < 4; mi++)
        af[mi] = *reinterpret_cast<const bf16x8*>(&sA[(wm + mi * 16 + r15) * 64 + sw * 8]);
#pragma unroll
      for (int ni = 0; ni < 4; ni++)
        bfr[ni] = *reinterpret_cast<const bf16x8*>(&sB[(wn + ni * 16 + r15) * 64 + sw * 8]);
#pragma unroll
      for (int mi = 0; mi < 4; mi++)
#pragma unroll
        for (int ni = 0; ni < 4; ni++)
          acc[mi][ni] = __builtin_amdgcn_mfma_f32_16x16x32_bf16(af[mi], bfr[ni], acc[mi][ni], 0, 0, 0);
    }
    __syncthreads();
  }

#pragma unroll
  for (int mi = 0; mi < 4; mi++) {
#pragma unroll
    for (int i = 0; i < 4; i++) {
      int t = m0 + wm + mi * 16 + quad * 4 + i;
#pragma unroll
      for (int ni = 0; ni < 4; ni++) {
        int n = n0 + wn + ni * 16 + r15;
        float v = acc[mi][ni][i];
        if (SPLIT) {
          if (n < CONVD) {
            Cb16[(size_t)t * CONVD + n] = __float2bfloat16(v);
          } else if (n < NPROJ) {
            int h = n - CONVD;
            float z = v + dt_bias[h];
            float sp = (z > 20.f) ? z : log1pf(__expf(z));
            dtb[t * NH + h] = sp;
          }
        } else {
          C[(size_t)t * NLD + n] = v;
        }
      }
    }
  }
}

// ---------------- K2: depthwise causal conv(4) + bias + SiLU (bf16) --------
__global__ __launch_bounds__(256) void k_conv(const __hip_bfloat16* __restrict__ xbc,
    const float* __restrict__ cw, const float* __restrict__ cb,
    __hip_bfloat16* __restrict__ xh, __hip_bfloat16* __restrict__ Bm,
    __hip_bfloat16* __restrict__ Cm) {
  int pi = blockIdx.x * 256 + threadIdx.x;
  if (pi >= CONVD / 2) return;
  int ch = pi * 2;
  int t = blockIdx.y;
  int l = t & (L_SEQ - 1);
  float a0 = cb[ch], a1 = cb[ch + 1];
  for (int j = 0; j < 4; j++) {
    int ls = l - 3 + j;
    if (ls >= 0) {
      __hip_bfloat162 v = *(const __hip_bfloat162*)(xbc + (size_t)(t - 3 + j) * CONVD + ch);
      a0 += __bfloat162float(v.x) * cw[j * CONVD + ch];
      a1 += __bfloat162float(v.y) * cw[j * CONVD + ch + 1];
    }
  }
  float s0 = a0 / (1.f + __expf(-a0));
  float s1 = a1 / (1.f + __expf(-a1));
  __hip_bfloat162 r;
  r.x = __float2bfloat16(s0);
  r.y = __float2bfloat16(s1);
  if (ch < DIN)                 *(__hip_bfloat162*)(xh + (size_t)t * DIN + ch) = r;
  else if (ch < DIN + DSTATE)   *(__hip_bfloat162*)(Bm + (size_t)t * DSTATE + ch - DIN) = r;
  else                          *(__hip_bfloat162*)(Cm + (size_t)t * DSTATE + ch - DIN - DSTATE) = r;
}

// ---------------- K3: per-(b,c,h) inclusive cumsum of A*dt + chunk decay ----
__global__ void k_acum(const float* __restrict__ dtb, const float* __restrict__ A_log,
                       float* __restrict__ acum, float* __restrict__ echunk) {
  int h = threadIdx.x;     // 32
  int bc = blockIdx.x;     // 0..127
  int base = bc * CH;
  float a = -__expf(A_log[h]);
  float s = 0.f;
  for (int l = 0; l < CH; l++) {
    s += a * dtb[(base + l) * NH + h];
    acum[(base + l) * NH + h] = s;
  }
  echunk[bc * NH + h] = __expf(s);
}

// ---------------- K4: fused SSD per (chunk, head): G -> P -> Ydiag, states --
// MFMA idiom: a-frag from X[row][k] (contig k), b-frag from Y[col][k] -> D = X.Y^T
#define PAD64 72     // padded stride for 64-long rows (bank-safe, 16B-aligned)
__global__ __launch_bounds__(256) void k_ssd1(
    const __hip_bfloat16* __restrict__ xh, const __hip_bfloat16* __restrict__ Bm,
    const __hip_bfloat16* __restrict__ Cm, const float* __restrict__ dtb,
    const float* __restrict__ acum, const float* __restrict__ Dp,
    __hip_bfloat16* __restrict__ ypart, __hip_bfloat16* __restrict__ states) {
  __shared__ __attribute__((aligned(16))) __hip_bfloat16 Cb[64 * 128];  // [l][n] swz
  __shared__ __attribute__((aligned(16))) __hip_bfloat16 Bb[64 * 128];  // [s][n] swz
  __shared__ __attribute__((aligned(16))) __hip_bfloat16 BdT[128 * PAD64]; // [n][l]
  __shared__ __attribute__((aligned(16))) __hip_bfloat16 xdT[64 * PAD64];  // [p][l]
  __shared__ __attribute__((aligned(16))) __hip_bfloat16 xhT[64 * PAD64];  // [p][l]
  __shared__ __attribute__((aligned(16))) __hip_bfloat16 P[64 * PAD64];    // [l][s]
  __shared__ float acv[64], dts[64], dec[64];
  int bc = blockIdx.x, h = blockIdx.y;
  int base = bc * CH;
  int tid = threadIdx.x, wid = tid >> 6, lane = tid & 63;
  int r15 = lane & 15, quad = lane >> 4;

  if (tid < 64) {
    float a = acum[(base + tid) * NH + h];
    acv[tid] = a;
    dts[tid] = dtb[(base + tid) * NH + h];
    float alast = acum[(base + 63) * NH + h];
    dec[tid] = __expf(alast - a);
  }
  __syncthreads();

  // stage Cb, Bb via async gload (XOR granule swizzle on global side)
  {
    int srow = lane >> 4, g = lane & 15;
    for (int c = 0; c < 4; c++) {
      int R0 = wid * 16 + c * 4;
      int r = R0 + srow;
      int gs = g ^ (r & 7);
      gload_lds16(Cm + (size_t)(base + r) * DSTATE + gs * 8, &Cb[R0 * DSTATE]);
      gload_lds16(Bm + (size_t)(base + r) * DSTATE + gs * 8, &Bb[R0 * DSTATE]);
    }
  }
  // stage BdT[n][l] = B[l][n]*dec[l]
  {
    int l = tid >> 2, c0 = (tid & 3) * 32;
    float dl = dec[l];
    const bf16x8* src = reinterpret_cast<const bf16x8*>(Bm + (size_t)(base + l) * DSTATE + c0);
    for (int v = 0; v < 4; v++) {
      bf16x8 vv = src[v];
      for (int j = 0; j < 8; j++) {
        int n = c0 + v * 8 + j;
        BdT[n * PAD64 + l] = __float2bfloat16(__bfloat162float((__hip_bfloat16)vv[j]) * dl);
      }
    }
  }
  // stage xdT[p][l] = xh[l][p]*dt[l], xhT[p][l] = xh[l][p]
  {
    int l = tid >> 2, c0 = (tid & 3) * 16;
    float dl = dts[l];
    const bf16x8* src = reinterpret_cast<const bf16x8*>(xh + (size_t)(base + l) * DIN + h * HD + c0);
    for (int v = 0; v < 2; v++) {
      bf16x8 vv = src[v];
      for (int j = 0; j < 8; j++) {
        int p = c0 + v * 8 + j;
        __hip_bfloat16 xv = (__hip_bfloat16)vv[j];
        xhT[p * PAD64 + l] = xv;
        xdT[p * PAD64 + l] = __float2bfloat16(__bfloat162float(xv) * dl);
      }
    }
  }
  __syncthreads();

  int wm = wid * 16;
  // --- G = C.B^T over this wave's 16-row strip
  f32x4 accg[4];
  f32x4 zz = {0.f, 0.f, 0.f, 0.f};
  for (int ct = 0; ct < 4; ct++) accg[ct] = zz;
#pragma unroll
  for (int ks = 0; ks < 4; ks++) {
    int arow = wm + r15;
    bf16x8 af = *reinterpret_cast<const bf16x8*>(&Cb[arow * 128 + (((ks * 4 + quad) ^ (arow & 7)) << 3)]);
#pragma unroll
    for (int ct = 0; ct < 4; ct++) {
      int brow = ct * 16 + r15;
      bf16x8 bfr = *reinterpret_cast<const bf16x8*>(&Bb[brow * 128 + (((ks * 4 + quad) ^ (brow & 7)) << 3)]);
      accg[ct] = __builtin_amdgcn_mfma_f32_16x16x32_bf16(af, bfr, accg[ct], 0, 0, 0);
    }
  }
  // --- P = mask(G * exp(acv_l - acv_s)) -> LDS bf16 (wave-private rows)
#pragma unroll
  for (int ct = 0; ct < 4; ct++) {
    int s = ct * 16 + r15;
    float as = acv[s];
#pragma unroll
    for (int i = 0; i < 4; i++) {
      int l = wm + quad * 4 + i;
      float pv = (s <= l) ? accg[ct][i] * __expf(acv[l] - as) : 0.f;
      P[l * PAD64 + s] = __float2bfloat16(pv);
    }
  }
  // --- Y_diag = P.xd + xh*D
  f32x4 accy[4];
  for (int ct = 0; ct < 4; ct++) accy[ct] = zz;
#pragma unroll
  for (int ks = 0; ks < 2; ks++) {
    int arow = wm + r15;
    bf16x8 af = *reinterpret_cast<const bf16x8*>(&P[arow * PAD64 + (ks * 4 + quad) * 8]);
#pragma unroll
    for (int ct = 0; ct < 4; ct++) {
      int brow = ct * 16 + r15;
      bf16x8 bfr = *reinterpret_cast<const bf16x8*>(&xdT[brow * PAD64 + (ks * 4 + quad) * 8]);
      accy[ct] = __builtin_amdgcn_mfma_f32_16x16x32_bf16(af, bfr, accy[ct], 0, 0, 0);
    }
  }
  float Dh = Dp[h];
#pragma unroll
  for (int ct = 0; ct < 4; ct++) {
    int p = ct * 16 + r15;
#pragma unroll
    for (int i = 0; i < 4; i++) {
      int l = wm + quad * 4 + i;
      float xv = __bfloat162float(xhT[p * PAD64 + l]);
      ypart[(size_t)(base + l) * DIN + h * HD + p] = __float2bfloat16(accy[ct][i] + xv * Dh);
    }
  }
  // --- states S[n][p] = sum_l Bdec[l][n]*xd[l][p]
  f32x4 accs[2][4];
  for (int rt = 0; rt < 2; rt++)
    for (int ct = 0; ct < 4; ct++) accs[rt][ct] = zz;
#pragma unroll
  for (int ks = 0; ks < 2; ks++) {
    bf16x8 bfr[4];
#pragma unroll
    for (int ct = 0; ct < 4; ct++) {
      int brow = ct * 16 + r15;
      bfr[ct] = *reinterpret_cast<const bf16x8*>(&xdT[brow * PAD64 + (ks * 4 + quad) * 8]);
    }
#pragma unroll
    for (int rt = 0; rt < 2; rt++) {
      int arow = wid * 32 + rt * 16 + r15;
      bf16x8 af = *reinterpret_cast<const bf16x8*>(&BdT[arow * PAD64 + (ks * 4 + quad) * 8]);
#pragma unroll
      for (int ct = 0; ct < 4; ct++)
        accs[rt][ct] = __builtin_amdgcn_mfma_f32_16x16x32_bf16(af, bfr[ct], accs[rt][ct], 0, 0, 0);
    }
  }
  size_t sbase = ((size_t)bc * NH + h) * (HD * DSTATE);
#pragma unroll
  for (int rt = 0; rt < 2; rt++) {
#pragma unroll
    for (int ct = 0; ct < 4; ct++) {
      int p = ct * 16 + r15;
#pragma unroll
      for (int i = 0; i < 4; i++) {
        int n = wid * 32 + rt * 16 + quad * 4 + i;
        states[sbase + (size_t)n * HD + p] = __float2bfloat16(accs[rt][ct][i]);
      }
    }
  }
}

// ---------------- K5: inter-chunk scan (in-place, layout [bc][h][n][p]) ----
__global__ __launch_bounds__(256) void k_scan(__hip_bfloat16* __restrict__ states,
    const float* __restrict__ echunk) {
  int idx = blockIdx.x * 256 + threadIdx.x;   // 524288
  int inner = idx & 8191;          // n*64+p
  int h = (idx >> 13) & 31;
  int b = idx >> 18;
  float run = 0.f;
  for (int c = 0; c < NCH; c++) {
    int bc = b * NCH + c;
    size_t off = ((size_t)bc * NH + h) * 8192 + inner;
    float tmp = __bfloat162float(states[off]);
    states[off] = __float2bfloat16(run);
    run = run * echunk[bc * NH + h] + tmp;
  }
}

// ---------------- K6: y += exp(acum) * (C . S_in^T), in-place bf16 ---------
#define PAD128 136
__global__ __launch_bounds__(256) void k_ssd2(
    const __hip_bfloat16* __restrict__ states, const __hip_bfloat16* __restrict__ Cm,
    const float* __restrict__ acum, __hip_bfloat16* __restrict__ y) {
  __shared__ __attribute__((aligned(16))) __hip_bfloat16 Cb[64 * 128];     // [l][n] swz
  __shared__ __attribute__((aligned(16))) __hip_bfloat16 SinT[64 * PAD128]; // [p][n]
  __shared__ __attribute__((aligned(16))) __hip_bfloat16 Yt[64 * 64];      // [l][p]
  __shared__ float aout[64];
  int bc = blockIdx.x, h = blockIdx.y;
  int base = bc * CH;
  int tid = threadIdx.x, wid = tid >> 6, lane = tid & 63;
  int r15 = lane & 15, quad = lane >> 4;

  if (tid < 64) aout[tid] = __expf(acum[(base + tid) * NH + h]);
  size_t sbase = ((size_t)bc * NH + h) * (HD * DSTATE);
  // stage Cb (swz) + Yt (natural)
  {
    int srow = lane >> 4, g = lane & 15;
    for (int c = 0; c < 4; c++) {
      int R0 = wid * 16 + c * 4;
      int r = R0 + srow;
      int gs = g ^ (r & 7);
      gload_lds16(Cm + (size_t)(base + r) * DSTATE + gs * 8, &Cb[R0 * DSTATE]);
    }
    for (int c = 0; c < 2; c++) {
      int R0 = wid * 16 + c * 8;
      int r = R0 + (lane >> 3);
      gload_lds16(y + (size_t)(base + r) * DIN + h * HD + (lane & 7) * 8, &Yt[R0 * 64]);
    }
  }
  // stage SinT[p][n] from states[n][p]
  {
    int n = tid >> 1, p0 = (tid & 1) * 32;
    const bf16x8* src = reinterpret_cast<const bf16x8*>(states + sbase + (size_t)n * HD + p0);
    for (int v = 0; v < 4; v++) {
      bf16x8 vv = src[v];
      for (int j = 0; j < 8; j++) {
        int p = p0 + v * 8 + j;
        SinT[p * PAD128 + n] = (__hip_bfloat16)vv[j];
      }
    }
  }
  __syncthreads();

  int wm = wid * 16;
  f32x4 acc[4];
  f32x4 zz = {0.f, 0.f, 0.f, 0.f};
  for (int ct = 0; ct < 4; ct++) acc[ct] = zz;
#pragma unroll
  for (int ks = 0; ks < 4; ks++) {
    int arow = wm + r15;
    bf16x8 af = *reinterpret_cast<const bf16x8*>(&Cb[arow * 128 + (((ks * 4 + quad) ^ (arow & 7)) << 3)]);
#pragma unroll
    for (int ct = 0; ct < 4; ct++) {
      int brow = ct * 16 + r15;
      bf16x8 bfr = *reinterpret_cast<const bf16x8*>(&SinT[brow * PAD128 + (ks * 4 + quad) * 8]);
      acc[ct] = __builtin_amdgcn_mfma_f32_16x16x32_bf16(af, bfr, acc[ct], 0, 0, 0);
    }
  }
#pragma unroll
  for (int ct = 0; ct < 4; ct++) {
    int p = ct * 16 + r15;
#pragma unroll
    for (int i = 0; i < 4; i++) {
      int l = wm + quad * 4 + i;
      float v = __bfloat162float(Yt[l * 64 + p]) + aout[l] * acc[ct][i];
      y[(size_t)(base + l) * DIN + h * HD + p] = __float2bfloat16(v);
    }
  }
}

extern "C" void kernel_launch(void* const* d_in, const int* in_sizes, int n_in,
                              void* d_out, int out_size, void* d_ws, size_t ws_size,
                              hipStream_t stream) {
  const float* x       = (const float*)d_in[0];
  const float* in_w    = (const float*)d_in[1];
  const float* conv_w  = (const float*)d_in[2];
  const float* conv_b  = (const float*)d_in[3];
  const float* dt_bias = (const float*)d_in[4];
  const float* A_log   = (const float*)d_in[5];
  const float* Dp      = (const float*)d_in[6];
  const float* out_w   = (const float*)d_in[7];
  float* out = (float*)d_out;

  char* cur = (char*)d_ws;
  auto alloc = [&](size_t bytes) {
    char* p = cur;
    cur += (bytes + 255) & ~(size_t)255;
    return p;
  };
  __hip_bfloat16* xbc   = (__hip_bfloat16*)alloc((size_t)T_TOK * CONVD * 2);
  float* dtb            = (float*)alloc((size_t)T_TOK * NH * 4);
  float* acum           = (float*)alloc((size_t)T_TOK * NH * 4);
  float* echunk         = (float*)alloc((size_t)NBC * NH * 4);
  __hip_bfloat16* xh    = (__hip_bfloat16*)alloc((size_t)T_TOK * DIN * 2);
  __hip_bfloat16* Bm    = (__hip_bfloat16*)alloc((size_t)T_TOK * DSTATE * 2);
  __hip_bfloat16* Cm    = (__hip_bfloat16*)alloc((size_t)T_TOK * DSTATE * 2);
  __hip_bfloat16* ybuf  = (__hip_bfloat16*)alloc((size_t)T_TOK * DIN * 2);
  __hip_bfloat16* states= (__hip_bfloat16*)alloc((size_t)NBC * NH * HD * DSTATE * 2);
  __hip_bfloat16* wib   = (__hip_bfloat16*)alloc((size_t)NPAD * DM * 2);
  __hip_bfloat16* wob   = (__hip_bfloat16*)alloc((size_t)DIN * DM * 2);
  __hip_bfloat16* xb    = states;   // alias: xb dead before k_ssd1 writes states

  k_cast   <<<dim3(T_TOK * DM / 1024), 256, 0, stream>>>(x, xb, T_TOK * DM / 4);
  k_wtrans <<<dim3(16, 38), 256, 0, stream>>>(in_w, wib, DM, DPROJ, PROJ_OFF, NPROJ);
  k_wtrans <<<dim3(32, 16), 256, 0, stream>>>(out_w, wob, DIN, DM, 0, DM);
  k_gemm_bt<DM, true><<<dim3(NPAD / 128, T_TOK / 128), 256, 0, stream>>>(
      xb, wib, nullptr, xbc, dtb, dt_bias, 0);
  k_conv   <<<dim3(5, T_TOK), 256, 0, stream>>>(xbc, conv_w, conv_b, xh, Bm, Cm);
  k_acum   <<<dim3(NBC),       32, 0, stream>>>(dtb, A_log, acum, echunk);
  k_ssd1   <<<dim3(NBC, NH),  256, 0, stream>>>(xh, Bm, Cm, dtb, acum, Dp, ybuf, states);
  k_scan   <<<dim3(2048),     256, 0, stream>>>(states, echunk);
  k_ssd2   <<<dim3(NBC, NH),  256, 0, stream>>>(states, Cm, acum, ybuf);
  k_gemm_bt<DIN, false><<<dim3(DM / 128, T_TOK / 128), 256, 0, stream>>>(
      ybuf, wob, out, nullptr, nullptr, nullptr, DM);
}

// Round 4
// 369.459 us; speedup vs baseline: 4.4168x; 1.1016x over previous
//
#include <hip/hip_runtime.h>
#include <hip/hip_bf16.h>
#include <math.h>
#include <stdint.h>

#define T_TOK 8192      // b*l
#define L_SEQ 4096
#define DM    1024
#define DIN   2048
#define DSTATE 128
#define NH    32
#define HD    64
#define CH    64        // chunk length
#define NCH   64        // chunks per batch
#define NBC   128       // B * NCH
#define CONVD 2304
#define NPROJ 2336      // columns of in_proj we actually need (z gate unused)
#define NPAD  2432      // NPROJ padded to multiple of 128
#define PROJ_OFF 2048
#define DPROJ 4384

typedef __bf16 bf16x8 __attribute__((ext_vector_type(8)));
typedef __bf16 bf16x4 __attribute__((ext_vector_type(4)));
typedef float f32x4 __attribute__((ext_vector_type(4)));

__device__ __forceinline__ void gload_lds16(const void* g, void* l) {
  __builtin_amdgcn_global_load_lds(
      (const __attribute__((address_space(1))) void*)(uintptr_t)g,
      (__attribute__((address_space(3))) void*)(uintptr_t)l, 16, 0, 0);
}

// ---------------- K0: fused preprocessing: cast x + transpose both weights --
__global__ __launch_bounds__(256) void k_pre(const float* __restrict__ x,
    __hip_bfloat16* __restrict__ xb, const float* __restrict__ in_w,
    __hip_bfloat16* __restrict__ wib, const float* __restrict__ out_w,
    __hip_bfloat16* __restrict__ wob) {
  __shared__ float s[64][65];
  int bid = blockIdx.x;
  if (bid < 8192) {                       // cast x -> bf16
    int i = (bid * 256 + threadIdx.x) * 4;
    float4 v = *(const float4*)(x + i);
    bf16x4 r;
    r[0] = (__bf16)v.x; r[1] = (__bf16)v.y; r[2] = (__bf16)v.z; r[3] = (__bf16)v.w;
    *(bf16x4*)(xb + i) = r;
    return;
  }
  const float* w; __hip_bfloat16* wt;
  int K, ldsrc, colOff, ncols, kx, ny;
  if (bid < 8800) {                       // in_proj weight transpose
    int b2 = bid - 8192; kx = b2 & 15; ny = b2 >> 4;
    w = in_w; wt = wib; K = DM; ldsrc = DPROJ; colOff = PROJ_OFF; ncols = NPROJ;
  } else {                                // out_proj weight transpose
    int b3 = bid - 8800; kx = b3 & 31; ny = b3 >> 5;
    w = out_w; wt = wob; K = DIN; ldsrc = DM; colOff = 0; ncols = DM;
  }
  int k0 = kx * 64, n0 = ny * 64;
  int c = threadIdx.x & 63, r0 = threadIdx.x >> 6;
  for (int i = 0; i < 16; i++) {
    int r = r0 + 4 * i;
    int ng = n0 + c;
    s[r][c] = (ng < ncols) ? w[(size_t)(k0 + r) * ldsrc + colOff + ng] : 0.f;
  }
  __syncthreads();
  for (int i = 0; i < 16; i++) {
    int a = r0 + 4 * i;
    wt[(size_t)(n0 + a) * K + k0 + c] = __float2bfloat16(s[c][a]);
  }
}

// ---------------- MFMA GEMM: C[M][N] = A[M][K] * Bt[N][K]^T -----------------
template <int KDIM, bool SPLIT>
__global__ __launch_bounds__(256) void k_gemm_bt(
    const __hip_bfloat16* __restrict__ A, const __hip_bfloat16* __restrict__ Bt,
    float* __restrict__ C, __hip_bfloat16* __restrict__ Cb16,
    float* __restrict__ dtb, const float* __restrict__ dt_bias, int NLD) {
  __shared__ __attribute__((aligned(16))) __hip_bfloat16 sA[128 * 64];
  __shared__ __attribute__((aligned(16))) __hip_bfloat16 sB[128 * 64];
  int tid = threadIdx.x;
  int wid = tid >> 6, lane = tid & 63;
  int m0 = blockIdx.y * 128, n0 = blockIdx.x * 128;
  int wm = (wid >> 1) * 64, wn = (wid & 1) * 64;
  int r15 = lane & 15, quad = lane >> 4;
  int srow = lane >> 3;
  int kcs = lane & 7;

  f32x4 acc[4][4];
  f32x4 zz = {0.f, 0.f, 0.f, 0.f};
  for (int mi = 0; mi < 4; mi++)
    for (int ni = 0; ni < 4; ni++) acc[mi][ni] = zz;

  const __hip_bfloat16* Abase = A + (size_t)m0 * KDIM;
  const __hip_bfloat16* Bbase = Bt + (size_t)n0 * KDIM;

  for (int k0 = 0; k0 < KDIM; k0 += 64) {
    for (int c = 0; c < 4; c++) {
      int R0 = (wid * 4 + c) * 8;
      int row = R0 + srow;
      int kcg = kcs ^ (row & 7);
      gload_lds16(Abase + (size_t)row * KDIM + k0 + kcg * 8, &sA[R0 * 64]);
      gload_lds16(Bbase + (size_t)row * KDIM + k0 + kcg * 8, &sB[R0 * 64]);
    }
    __syncthreads();
#pragma unroll
    for (int s = 0; s < 2; s++) {
      int sw = ((s << 2) | quad) ^ (r15 & 7);
      bf16x8 af[4], bfr[4];
#pragma unroll
      for (int mi = 0; mi < 4; mi++)
        af[mi] = *reinterpret_cast<const bf16x8*>(&sA[(wm + mi * 16 + r15) * 64 + sw * 8]);
#pragma unroll
      for (int ni = 0; ni < 4; ni++)
        bfr[ni] = *reinterpret_cast<const bf16x8*>(&sB[(wn + ni * 16 + r15) * 64 + sw * 8]);
#pragma unroll
      for (int mi = 0; mi < 4; mi++)
#pragma unroll
        for (int ni = 0; ni < 4; ni++)
          acc[mi][ni] = __builtin_amdgcn_mfma_f32_16x16x32_bf16(af[mi], bfr[ni], acc[mi][ni], 0, 0, 0);
    }
    __syncthreads();
  }

#pragma unroll
  for (int mi = 0; mi < 4; mi++) {
#pragma unroll
    for (int i = 0; i < 4; i++) {
      int t = m0 + wm + mi * 16 + quad * 4 + i;
#pragma unroll
      for (int ni = 0; ni < 4; ni++) {
        int n = n0 + wn + ni * 16 + r15;
        float v = acc[mi][ni][i];
        if (SPLIT) {
          if (n < CONVD) {
            Cb16[(size_t)t * CONVD + n] = __float2bfloat16(v);
          } else if (n < NPROJ) {
            int h = n - CONVD;
            float z = v + dt_bias[h];
            float sp = (z > 20.f) ? z : log1pf(__expf(z));
            dtb[t * NH + h] = sp;
          }
        } else {
          C[(size_t)t * NLD + n] = v;
        }
      }
    }
  }
}

// ---------------- K2: depthwise causal conv(4) + bias + SiLU (4 ch/thread) --
__global__ __launch_bounds__(256) void k_conv(const __hip_bfloat16* __restrict__ xbc,
    const float* __restrict__ cw, const float* __restrict__ cb,
    __hip_bfloat16* __restrict__ xh, __hip_bfloat16* __restrict__ Bm,
    __hip_bfloat16* __restrict__ Cm) {
  int pi = blockIdx.x * 256 + threadIdx.x;
  if (pi >= CONVD / 4) return;
  int ch = pi * 4;
  int t = blockIdx.y;
  int l = t & (L_SEQ - 1);
  float4 cb4 = *(const float4*)(cb + ch);
  float acc[4] = {cb4.x, cb4.y, cb4.z, cb4.w};
#pragma unroll
  for (int j = 0; j < 4; j++) {
    int ls = l - 3 + j;
    if (ls >= 0) {
      bf16x4 v = *(const bf16x4*)(xbc + (size_t)(t - 3 + j) * CONVD + ch);
      float4 w4 = *(const float4*)(cw + j * CONVD + ch);
      acc[0] += (float)v[0] * w4.x;
      acc[1] += (float)v[1] * w4.y;
      acc[2] += (float)v[2] * w4.z;
      acc[3] += (float)v[3] * w4.w;
    }
  }
  bf16x4 r;
#pragma unroll
  for (int i = 0; i < 4; i++) {
    float sv = acc[i] / (1.f + __expf(-acc[i]));
    r[i] = (__bf16)sv;
  }
  if (ch < DIN)                 *(bf16x4*)(xh + (size_t)t * DIN + ch) = r;
  else if (ch < DIN + DSTATE)   *(bf16x4*)(Bm + (size_t)t * DSTATE + ch - DIN) = r;
  else                          *(bf16x4*)(Cm + (size_t)t * DSTATE + ch - DIN - DSTATE) = r;
}

// ---------------- K3: per-(b,c,h) inclusive cumsum of A*dt + chunk decay ----
__global__ void k_acum(const float* __restrict__ dtb, const float* __restrict__ A_log,
                       float* __restrict__ acum, float* __restrict__ echunk) {
  int h = threadIdx.x;     // 32
  int bc = blockIdx.x;     // 0..127
  int base = bc * CH;
  float a = -__expf(A_log[h]);
  float s = 0.f;
  for (int l = 0; l < CH; l++) {
    s += a * dtb[(base + l) * NH + h];
    acum[(base + l) * NH + h] = s;
  }
  echunk[bc * NH + h] = __expf(s);
}

// ---------------- K4: fused SSD per (chunk, 8 heads): G once -> per-head ----
// All transposed LDS arrays use stride-64 XOR-granule layout: element (row, k)
// stored at row*64 + ((k>>3)^(row&7))*8 + (k&7). Store/read swizzles cancel.
__global__ __launch_bounds__(256) void k_ssd1(
    const __hip_bfloat16* __restrict__ xh, const __hip_bfloat16* __restrict__ Bm,
    const __hip_bfloat16* __restrict__ Cm, const float* __restrict__ dtb,
    const float* __restrict__ acum, const float* __restrict__ Dp,
    __hip_bfloat16* __restrict__ ypart, __hip_bfloat16* __restrict__ statesT) {
  __shared__ __attribute__((aligned(16))) char smem[32768 + 8192 + 6144];
  __hip_bfloat16* Cb  = (__hip_bfloat16*)smem;            // 64x128 swz (phase 1)
  __hip_bfloat16* Bb  = Cb + 64 * 128;                    // 64x128 swz (phase 1)
  __hip_bfloat16* BT  = (__hip_bfloat16*)smem;            // 128x64 [n][l] (phase 2, alias)
  __hip_bfloat16* xdT = BT + 128 * 64;                    // 64x64 [p][l] x*dt
  __hip_bfloat16* xsT = xdT + 64 * 64;                    // 64x64 [p][l] x*dt*dec
  __hip_bfloat16* P   = (__hip_bfloat16*)(smem + 32768);  // 64x64 [l][s]
  float* acvA = (float*)(smem + 32768 + 8192);            // [8][64]
  float* dtsA = acvA + 512;
  float* decA = dtsA + 512;

  int bc = blockIdx.x, h0 = blockIdx.y * 8;
  int base = bc * CH;
  int tid = threadIdx.x, wid = tid >> 6, lane = tid & 63;
  int r15 = lane & 15, quad = lane >> 4;
  int wm = wid * 16;
  f32x4 zz = {0.f, 0.f, 0.f, 0.f};

  // preload per-head scalars (8 heads x 64 positions)
  for (int i = 0; i < 2; i++) {
    int idx = tid + 256 * i;
    int hh = idx >> 6, l = idx & 63;
    int h = h0 + hh;
    float a = acum[(base + l) * NH + h];
    float alast = acum[(base + 63) * NH + h];
    acvA[hh * 64 + l] = a;
    dtsA[hh * 64 + l] = dtb[(base + l) * NH + h];
    decA[hh * 64 + l] = __expf(alast - a);
  }
  // stage Cb/Bb via async gload (row-granule XOR swizzle on global side)
  {
    int srow = lane >> 4, g = lane & 15;
    for (int c = 0; c < 4; c++) {
      int R0 = wid * 16 + c * 4;
      int r = R0 + srow;
      int gs = g ^ (r & 7);
      gload_lds16(Cm + (size_t)(base + r) * DSTATE + gs * 8, &Cb[R0 * DSTATE]);
      gload_lds16(Bm + (size_t)(base + r) * DSTATE + gs * 8, &Bb[R0 * DSTATE]);
    }
  }
  __syncthreads();

  // --- G = C.B^T once: wave strip rows wm..wm+15 x all 64 s (K=128)
  f32x4 accg[4];
  for (int ct = 0; ct < 4; ct++) accg[ct] = zz;
#pragma unroll
  for (int ks = 0; ks < 4; ks++) {
    int arow = wm + r15;
    bf16x8 af = *(const bf16x8*)&Cb[arow * 128 + (((ks * 4 + quad) ^ (r15 & 7)) << 3)];
#pragma unroll
    for (int ct = 0; ct < 4; ct++) {
      int brow = ct * 16 + r15;
      bf16x8 bfr = *(const bf16x8*)&Bb[brow * 128 + (((ks * 4 + quad) ^ (r15 & 7)) << 3)];
      accg[ct] = __builtin_amdgcn_mfma_f32_16x16x32_bf16(af, bfr, accg[ct], 0, 0, 0);
    }
  }
  __syncthreads();   // Cb/Bb dead; region reused below

  int l0 = (tid & 15) * 4;     // 4 consecutive l (same granule: l0%8 in {0,4})
  int q0 = tid >> 4;           // 0..15
  int go = l0 & 7;             // offset within granule
  int gl = l0 >> 3;            // true granule of l0

  for (int hh = 0; hh < 8; hh++) {
    int h = h0 + hh;
    if (hh == 0) {
      // build BT[n][l] once (head-independent, decay folded into xs)
      int n0 = q0 * 8;
      __bf16 tmp[8][4];
#pragma unroll
      for (int dl = 0; dl < 4; dl++) {
        bf16x8 bv = *(const bf16x8*)(Bm + (size_t)(base + l0 + dl) * DSTATE + n0);
#pragma unroll
        for (int dn = 0; dn < 8; dn++) tmp[dn][dl] = bv[dn];
      }
#pragma unroll
      for (int dn = 0; dn < 8; dn++) {
        int n = n0 + dn;
        bf16x4 pk = {tmp[dn][0], tmp[dn][1], tmp[dn][2], tmp[dn][3]};
        *(bf16x4*)&BT[n * 64 + ((gl ^ (n & 7)) << 3) + go] = pk;
      }
    }
    // build xdT (x*dt) and xsT (x*dt*dec) for this head: 4l x 4p per thread
    {
      int p0 = q0 * 4;
      __bf16 td[4][4], ts[4][4];
#pragma unroll
      for (int dl = 0; dl < 4; dl++) {
        int l = l0 + dl;
        bf16x4 xv = *(const bf16x4*)(xh + (size_t)(base + l) * DIN + h * HD + p0);
        float dt = dtsA[hh * 64 + l];
        float ds = dt * decA[hh * 64 + l];
#pragma unroll
        for (int dp = 0; dp < 4; dp++) {
          float xf = (float)xv[dp];
          td[dp][dl] = (__bf16)(xf * dt);
          ts[dp][dl] = (__bf16)(xf * ds);
        }
      }
#pragma unroll
      for (int dp = 0; dp < 4; dp++) {
        int p = p0 + dp;
        int off = p * 64 + ((gl ^ (p & 7)) << 3) + go;
        bf16x4 pd = {td[dp][0], td[dp][1], td[dp][2], td[dp][3]};
        bf16x4 ps = {ts[dp][0], ts[dp][1], ts[dp][2], ts[dp][3]};
        *(bf16x4*)&xdT[off] = pd;
        *(bf16x4*)&xsT[off] = ps;
      }
    }
    __syncthreads();

    // --- P = mask(G * decay) -> LDS (wave-private rows wm..wm+15)
#pragma unroll
    for (int ct = 0; ct < 4; ct++) {
      int s = ct * 16 + r15;
      float as = acvA[hh * 64 + s];
#pragma unroll
      for (int i = 0; i < 4; i++) {
        int l = wm + quad * 4 + i;
        float pv = (s <= l) ? accg[ct][i] * __expf(acvA[hh * 64 + l] - as) : 0.f;
        P[l * 64 + (((s >> 3) ^ (l & 7)) << 3) + (s & 7)] = __float2bfloat16(pv);
      }
    }
    // --- Y_diag = P.xd (K=64) + xh*D
    f32x4 accy[4];
    for (int ct = 0; ct < 4; ct++) accy[ct] = zz;
#pragma unroll
    for (int ks = 0; ks < 2; ks++) {
      int arow = wm + r15;
      bf16x8 af = *(const bf16x8*)&P[arow * 64 + (((ks * 4 + quad) ^ (r15 & 7)) << 3)];
#pragma unroll
      for (int ct = 0; ct < 4; ct++) {
        int brow = ct * 16 + r15;
        bf16x8 bfr = *(const bf16x8*)&xdT[brow * 64 + (((ks * 4 + quad) ^ (r15 & 7)) << 3)];
        accy[ct] = __builtin_amdgcn_mfma_f32_16x16x32_bf16(af, bfr, accy[ct], 0, 0, 0);
      }
    }
    float Dh = Dp[h];
#pragma unroll
    for (int ct = 0; ct < 4; ct++) {
      int p = ct * 16 + r15;
#pragma unroll
      for (int i = 0; i < 4; i++) {
        int l = wm + quad * 4 + i;
        float xv = __bfloat162float(xh[(size_t)(base + l) * DIN + h * HD + p]);
        ypart[(size_t)(base + l) * DIN + h * HD + p] = __float2bfloat16(accy[ct][i] + xv * Dh);
      }
    }
    // --- S^T[p][n] = sum_l xs[l][p] * B[l][n]  (K=64, wave strip over p)
    f32x4 accs[8];
    for (int ct = 0; ct < 8; ct++) accs[ct] = zz;
#pragma unroll
    for (int ks = 0; ks < 2; ks++) {
      int arow = wm + r15;   // p row
      bf16x8 af = *(const bf16x8*)&xsT[arow * 64 + (((ks * 4 + quad) ^ (r15 & 7)) << 3)];
#pragma unroll
      for (int ct = 0; ct < 8; ct++) {
        int brow = ct * 16 + r15;   // n row
        bf16x8 bfr = *(const bf16x8*)&BT[brow * 64 + (((ks * 4 + quad) ^ (r15 & 7)) << 3)];
        accs[ct] = __builtin_amdgcn_mfma_f32_16x16x32_bf16(af, bfr, accs[ct], 0, 0, 0);
      }
    }
    size_t sbase = ((size_t)bc * NH + h) * (HD * DSTATE);
#pragma unroll
    for (int ct = 0; ct < 8; ct++) {
      int n = ct * 16 + r15;
#pragma unroll
      for (int i = 0; i < 4; i++) {
        int p = wm + quad * 4 + i;
        statesT[sbase + (size_t)p * DSTATE + n] = __float2bfloat16(accs[ct][i]);
      }
    }
    __syncthreads();   // before next head overwrites xdT/xsT
  }
}

// ---------------- K5: inter-chunk scan (in-place, layout [bc][h][p][n]) ----
__global__ __launch_bounds__(256) void k_scan(__hip_bfloat16* __restrict__ states,
    const float* __restrict__ echunk) {
  int idx = blockIdx.x * 256 + threadIdx.x;   // 524288
  int inner = idx & 8191;          // p*128+n
  int h = (idx >> 13) & 31;
  int b = idx >> 18;
  float run = 0.f;
  for (int c = 0; c < NCH; c++) {
    int bc = b * NCH + c;
    size_t off = ((size_t)bc * NH + h) * 8192 + inner;
    float tmp = __bfloat162float(states[off]);
    states[off] = __float2bfloat16(run);
    run = run * echunk[bc * NH + h] + tmp;
  }
}

// ---------------- K6: y += exp(acum) * (C . S_in^T), in-place bf16 ---------
__global__ __launch_bounds__(256) void k_ssd2(
    const __hip_bfloat16* __restrict__ statesT, const __hip_bfloat16* __restrict__ Cm,
    const float* __restrict__ acum, __hip_bfloat16* __restrict__ y) {
  __shared__ __attribute__((aligned(16))) __hip_bfloat16 Cb[64 * 128];  // [l][n] swz
  __shared__ __attribute__((aligned(16))) __hip_bfloat16 Sb[64 * 128];  // [p][n] swz
  __shared__ __attribute__((aligned(16))) __hip_bfloat16 Yt[64 * 64];   // [l][p]
  __shared__ float aout[64];
  int bc = blockIdx.x, h = blockIdx.y;
  int base = bc * CH;
  int tid = threadIdx.x, wid = tid >> 6, lane = tid & 63;
  int r15 = lane & 15, quad = lane >> 4;
  int wm = wid * 16;

  if (tid < 64) aout[tid] = __expf(acum[(base + tid) * NH + h]);
  size_t sbase = ((size_t)bc * NH + h) * (HD * DSTATE);
  {
    int srow = lane >> 4, g = lane & 15;
    for (int c = 0; c < 4; c++) {
      int R0 = wid * 16 + c * 4;
      int r = R0 + srow;
      int gs = g ^ (r & 7);
      gload_lds16(Cm + (size_t)(base + r) * DSTATE + gs * 8, &Cb[R0 * DSTATE]);
      gload_lds16(statesT + sbase + (size_t)r * DSTATE + gs * 8, &Sb[R0 * DSTATE]);
    }
    for (int c = 0; c < 2; c++) {
      int R0 = wid * 16 + c * 8;
      int r = R0 + (lane >> 3);
      gload_lds16(y + (size_t)(base + r) * DIN + h * HD + (lane & 7) * 8, &Yt[R0 * 64]);
    }
  }
  __syncthreads();

  f32x4 acc[4];
  f32x4 zz = {0.f, 0.f, 0.f, 0.f};
  for (int ct = 0; ct < 4; ct++) acc[ct] = zz;
#pragma unroll
  for (int ks = 0; ks < 4; ks++) {
    int arow = wm + r15;
    bf16x8 af = *(const bf16x8*)&Cb[arow * 128 + (((ks * 4 + quad) ^ (r15 & 7)) << 3)];
#pragma unroll
    for (int ct = 0; ct < 4; ct++) {
      int brow = ct * 16 + r15;
      bf16x8 bfr = *(const bf16x8*)&Sb[brow * 128 + (((ks * 4 + quad) ^ (r15 & 7)) << 3)];
      acc[ct] = __builtin_amdgcn_mfma_f32_16x16x32_bf16(af, bfr, acc[ct], 0, 0, 0);
    }
  }
#pragma unroll
  for (int ct = 0; ct < 4; ct++) {
    int p = ct * 16 + r15;
#pragma unroll
    for (int i = 0; i < 4; i++) {
      int l = wm + quad * 4 + i;
      float v = __bfloat162float(Yt[l * 64 + p]) + aout[l] * acc[ct][i];
      y[(size_t)(base + l) * DIN + h * HD + p] = __float2bfloat16(v);
    }
  }
}

extern "C" void kernel_launch(void* const* d_in, const int* in_sizes, int n_in,
                              void* d_out, int out_size, void* d_ws, size_t ws_size,
                              hipStream_t stream) {
  const float* x       = (const float*)d_in[0];
  const float* in_w    = (const float*)d_in[1];
  const float* conv_w  = (const float*)d_in[2];
  const float* conv_b  = (const float*)d_in[3];
  const float* dt_bias = (const float*)d_in[4];
  const float* A_log   = (const float*)d_in[5];
  const float* Dp      = (const float*)d_in[6];
  const float* out_w   = (const float*)d_in[7];
  float* out = (float*)d_out;

  char* cur = (char*)d_ws;
  auto alloc = [&](size_t bytes) {
    char* p = cur;
    cur += (bytes + 255) & ~(size_t)255;
    return p;
  };
  __hip_bfloat16* xbc   = (__hip_bfloat16*)alloc((size_t)T_TOK * CONVD * 2);
  float* dtb            = (float*)alloc((size_t)T_TOK * NH * 4);
  float* acum           = (float*)alloc((size_t)T_TOK * NH * 4);
  float* echunk         = (float*)alloc((size_t)NBC * NH * 4);
  __hip_bfloat16* xh    = (__hip_bfloat16*)alloc((size_t)T_TOK * DIN * 2);
  __hip_bfloat16* Bm    = (__hip_bfloat16*)alloc((size_t)T_TOK * DSTATE * 2);
  __hip_bfloat16* Cm    = (__hip_bfloat16*)alloc((size_t)T_TOK * DSTATE * 2);
  __hip_bfloat16* ybuf  = (__hip_bfloat16*)alloc((size_t)T_TOK * DIN * 2);
  __hip_bfloat16* states= (__hip_bfloat16*)alloc((size_t)NBC * NH * HD * DSTATE * 2);
  __hip_bfloat16* wib   = (__hip_bfloat16*)alloc((size_t)NPAD * DM * 2);
  __hip_bfloat16* wob   = (__hip_bfloat16*)alloc((size_t)DIN * DM * 2);
  __hip_bfloat16* xb    = states;   // alias: xb dead before k_ssd1 writes states

  k_pre    <<<dim3(9312), 256, 0, stream>>>(x, xb, in_w, wib, out_w, wob);
  k_gemm_bt<DM, true><<<dim3(NPAD / 128, T_TOK / 128), 256, 0, stream>>>(
      xb, wib, nullptr, xbc, dtb, dt_bias, 0);
  k_conv   <<<dim3(3, T_TOK), 256, 0, stream>>>(xbc, conv_w, conv_b, xh, Bm, Cm);
  k_acum   <<<dim3(NBC),       32, 0, stream>>>(dtb, A_log, acum, echunk);
  k_ssd1   <<<dim3(NBC, 4),   256, 0, stream>>>(xh, Bm, Cm, dtb, acum, Dp, ybuf, states);
  k_scan   <<<dim3(2048),     256, 0, stream>>>(states, echunk);
  k_ssd2   <<<dim3(NBC, NH),  256, 0, stream>>>(states, Cm, acum, ybuf);
  k_gemm_bt<DIN, false><<<dim3(DM / 128, T_TOK / 128), 256, 0, stream>>>(
      ybuf, wob, out, nullptr, nullptr, nullptr, DM);
}